// Round 6
// baseline (240.948 us; speedup 1.0000x reference)
//
#include <hip/hip_runtime.h>
#include <math.h>

#define Hh 512
#define Ww 512
#define Bb 8
#define CI 32
#define CO 32
#define HM 16   // kx modes kept
#define KYp 32  // packed ky modes (0..15 and 496..511)

static constexpr float TWO_PI = 6.28318530717958647692f;

// workspace layout (float offsets)
#define F_OFF  4194304u   // [B*CI][32][16][2] = 262,144 floats
#define G_OFF  4456448u   // [B*CO][32][16][2] = 262,144 floats
#define g_OFF  4718592u   // [B*CO][512][16][2] = 4,194,304 floats
// E  (bf16 phase-1 DFT frags, 32 KB)  at g_OFF          (dead before t1)
// E2c (bf16 phase-2 DFT frags, 64 KB) at g_OFF + 8192   (dead before t1)

using short8 = __attribute__((ext_vector_type(8))) short;
using f32x16 = __attribute__((ext_vector_type(16))) float;

__device__ inline unsigned short bf16_rn(float f) {
  unsigned u = __float_as_uint(f);
  u += 0x7FFFu + ((u >> 16) & 1u);
  return (unsigned short)(u >> 16);
}

// exact split of 4 floats into hi(bf16-trunc) + lo(residual as bf16)
__device__ inline void split4(float4 v, uint2& h2, uint2& l2) {
  unsigned u0 = __float_as_uint(v.x), u1 = __float_as_uint(v.y);
  unsigned u2 = __float_as_uint(v.z), u3 = __float_as_uint(v.w);
  float f0 = v.x - __uint_as_float(u0 & 0xFFFF0000u);
  float f1 = v.y - __uint_as_float(u1 & 0xFFFF0000u);
  float f2 = v.z - __uint_as_float(u2 & 0xFFFF0000u);
  float f3 = v.w - __uint_as_float(u3 & 0xFFFF0000u);
  h2.x = (u1 & 0xFFFF0000u) | (u0 >> 16);
  h2.y = (u3 & 0xFFFF0000u) | (u2 >> 16);
  l2.x = (__float_as_uint(f1) & 0xFFFF0000u) | (__float_as_uint(f0) >> 16);
  l2.y = (__float_as_uint(f3) & 0xFFFF0000u) | (__float_as_uint(f2) >> 16);
}

// --------- E init: both DFT-matrix fragment tables -----------------------
// E   [kk(32)][lane][8]: k = kk*16 + 8*(l>>5)+j over w; col = l&31 = 2kx+c
// E2c [mt(2)][kk(32)][lane][8]: kyc = l&31 = 2*kyp_loc+c; h = kk*16+8*(l>>5)+j
__global__ __launch_bounds__(256) void e_init_kernel(float* __restrict__ Ef) {
  unsigned short* E = (unsigned short*)Ef;
  int idx = blockIdx.x * 256 + threadIdx.x;   // 0..49151
  if (idx < 16384) {
    int kk = idx >> 9;
    int l = (idx >> 3) & 63;
    int j = idx & 7;
    int k = kk * 16 + 8 * (l >> 5) + j;
    int col = l & 31;
    int kx = col >> 1;
    int t = (kx * k) & 511;
    float sv, cv;
    sincosf(TWO_PI * (float)t / 512.0f, &sv, &cv);
    E[idx] = bf16_rn((col & 1) ? -sv : cv);
  } else {
    int idx2 = idx - 16384;
    int mt = idx2 >> 14;
    int rem = idx2 & 16383;
    int kk = rem >> 9;
    int l = (rem >> 3) & 63;
    int j = rem & 7;
    int h = kk * 16 + 8 * (l >> 5) + j;
    int kyc = l & 31;
    int kyp = mt * 16 + (kyc >> 1);
    int ky = (kyp < 16) ? kyp : (kyp + 480);
    int t = (ky * h) & 511;
    float sv, cv;
    sincosf(TWO_PI * (float)t / 512.0f, &sv, &cv);
    E[idx] = bf16_rn((kyc & 1) ? -sv : cv);
  }
}

// ---------------- fwd: x image -> F (row-contiguous HBM reads) -----------
// One block per (b,i), 512 thr = 8 waves, 1 block/CU (132 KB LDS).
// 16 steps of 32 contiguous rows: stage rows (1 KB-contiguous loads) ->
// LDS transpose to A-frags -> MFMA-1 (K split 8 ways over waves) ->
// LDS reduce -> 32 A-rows -> rank-32 phase-2 MFMA update (acc2).
__global__ __launch_bounds__(512) void fwd_kernel(const float* __restrict__ x,
                                                  const float* __restrict__ Ef,
                                                  const float* __restrict__ E2f,
                                                  float* __restrict__ F) {
  __shared__ char lds[135168];
  short* E2l = (short*)lds;                 // [mt 2][kk 32][64][8]  64 KB
  short* Xh  = (short*)(lds + 65536);       // [kc 32][64][8]        32 KB
  short* Xl  = (short*)(lds + 98304);       //                       32 KB
  float* red = (float*)(lds + 65536);       // alias Xh: [w8][q4][64][4] 32 KB
  short* Ah  = (short*)(lds + 131072);      // [kc2 2][64][8]         2 KB
  short* Al  = (short*)(lds + 133120);      //                        2 KB
  float* Pbuf = (float*)(lds + 65536);      // final reduce (alias)  32 KB

  const int tid = threadIdx.x;
  const int l = tid & 63;
  const int wid = tid >> 6;
  const int bi = blockIdx.x;
  const float* xb = x + (size_t)bi * (Hh * Ww);

  // stage E2c (64 KB), coalesced
  {
    const float4* Eg = (const float4*)E2f;
    float4* El4 = (float4*)E2l;
    #pragma unroll
    for (int j = 0; j < 8; ++j) El4[tid + j * 512] = Eg[tid + j * 512];
  }
  // E1 fragments for this wave's 4 w-chunks -> 16 VGPR
  short8 e1[4];
  {
    const short* Eg = (const short*)Ef;
    #pragma unroll
    for (int c = 0; c < 4; ++c)
      e1[c] = *(const short8*)(Eg + ((size_t)(4 * wid + c) * 64 + l) * 8);
  }

  // staging geometry: wave handles rows s*32 + wid*4 + j (j=0..3);
  // lane l covers cols 4l..4l+3 (first KB) and 256+4l.. (second KB)
  const int hb = (l >> 1) & 1;      // fragment lane-half from col group
  const int jfr = 4 * (l & 1);      // j' within fragment
  const int kc0 = l >> 2;           // w-chunk (first half)

  float4 rv[8];
  #pragma unroll
  for (int j = 0; j < 4; ++j) {
    const float* rowp = xb + (size_t)(wid * 4 + j) * 512;
    rv[2 * j]     = *(const float4*)(rowp + 4 * l);
    rv[2 * j + 1] = *(const float4*)(rowp + 256 + 4 * l);
  }

  f32x16 acc1 = {0.f,0.f,0.f,0.f,0.f,0.f,0.f,0.f,0.f,0.f,0.f,0.f,0.f,0.f,0.f,0.f};
  f32x16 acc2 = {0.f,0.f,0.f,0.f,0.f,0.f,0.f,0.f,0.f,0.f,0.f,0.f,0.f,0.f,0.f,0.f};

  const int mt2 = wid & 1, kc2w = (wid >> 1) & 1, part2 = wid >> 2;

  for (int s = 0; s < 16; ++s) {
    // ---- phase-2 MFMA for previous step (reads Ah/Al + E2l)
    if (s > 0) {
      short8 a2 = *(const short8*)&E2l[((mt2 * 32 + ((s - 1) * 2 + kc2w)) * 64 + l) * 8];
      short8 b2 = part2 ? *(const short8*)&Al[(kc2w * 64 + l) * 8]
                        : *(const short8*)&Ah[(kc2w * 64 + l) * 8];
      acc2 = __builtin_amdgcn_mfma_f32_32x32x16_bf16(a2, b2, acc2, 0, 0, 0);
    }
    // ---- scatter rv -> X fragments (XOR lane swizzle per chunk)
    #pragma unroll
    for (int j = 0; j < 4; ++j) {
      #pragma unroll
      for (int hf = 0; hf < 2; ++hf) {
        int kc = hf * 16 + kc0;
        int lanep = (wid * 4 + j) + 32 * hb;
        int off = ((kc * 64) + (lanep ^ (kc & 7))) * 8 + jfr;
        uint2 h2, l2;
        split4(rv[2 * j + hf], h2, l2);
        *(uint2*)&Xh[off] = h2;
        *(uint2*)&Xl[off] = l2;
      }
    }
    // ---- issue next step's loads (contiguous rows, fly under compute)
    if (s < 15) {
      #pragma unroll
      for (int j = 0; j < 4; ++j) {
        const float* rowp = xb + (size_t)((s + 1) * 32 + wid * 4 + j) * 512;
        rv[2 * j]     = *(const float4*)(rowp + 4 * l);
        rv[2 * j + 1] = *(const float4*)(rowp + 256 + 4 * l);
      }
    }
    __syncthreads();
    // ---- MFMA-1: this wave's 4 w-chunks, hi+lo
    #pragma unroll
    for (int c = 0; c < 4; ++c) {
      int kc = 4 * wid + c;
      int slot = ((kc * 64) + (l ^ (kc & 7))) * 8;
      short8 hi = *(const short8*)&Xh[slot];
      short8 lo = *(const short8*)&Xl[slot];
      acc1 = __builtin_amdgcn_mfma_f32_32x32x16_bf16(hi, e1[c], acc1, 0, 0, 0);
      acc1 = __builtin_amdgcn_mfma_f32_32x32x16_bf16(lo, e1[c], acc1, 0, 0, 0);
    }
    __syncthreads();
    // ---- write K-partials (X-frag region is dead now)
    #pragma unroll
    for (int q = 0; q < 4; ++q)
      *(float4*)&red[((wid * 4 + q) * 64 + l) * 4] =
          make_float4(acc1[4*q], acc1[4*q+1], acc1[4*q+2], acc1[4*q+3]);
    #pragma unroll
    for (int r = 0; r < 16; ++r) acc1[r] = 0.f;
    __syncthreads();
    // ---- reduce 8 partials -> 32 A-rows -> A fragments (hi/lo)
    if (wid < 4) {
      const int q = wid;
      float4 sum = make_float4(0.f, 0.f, 0.f, 0.f);
      #pragma unroll
      for (int w = 0; w < 8; ++w) {
        float4 v = *(const float4*)&red[((w * 4 + q) * 64 + l) * 4];
        sum.x += v.x; sum.y += v.y; sum.z += v.z; sum.w += v.w;
      }
      uint2 h2, l2;
      split4(sum, h2, l2);
      int off = ((q >> 1) * 64 + ((l & 31) + 32 * (q & 1))) * 8 + 4 * (l >> 5);
      *(uint2*)&Ah[off] = h2;
      *(uint2*)&Al[off] = l2;
    }
    __syncthreads();
  }
  // final phase-2 MFMA (s = 15)
  {
    short8 a2 = *(const short8*)&E2l[((mt2 * 32 + (15 * 2 + kc2w)) * 64 + l) * 8];
    short8 b2 = part2 ? *(const short8*)&Al[(kc2w * 64 + l) * 8]
                      : *(const short8*)&Ah[(kc2w * 64 + l) * 8];
    acc2 = __builtin_amdgcn_mfma_f32_32x32x16_bf16(a2, b2, acc2, 0, 0, 0);
  }
  // write acc2 partials -> Pbuf (region free since last reduce read)
  #pragma unroll
  for (int r4 = 0; r4 < 4; ++r4)
    *(float4*)&Pbuf[((wid * 4 + r4) * 64 + l) * 4] =
        make_float4(acc2[4*r4], acc2[4*r4+1], acc2[4*r4+2], acc2[4*r4+3]);
  __syncthreads();

  if (wid < 2) {
    const int mt = wid;
    float S[16];
    #pragma unroll
    for (int r = 0; r < 16; ++r) S[r] = 0.f;
    #pragma unroll
    for (int p = 0; p < 4; ++p) {
      #pragma unroll
      for (int r4 = 0; r4 < 4; ++r4) {
        float4 v = *(const float4*)&Pbuf[(((mt + 2 * p) * 4 + r4) * 64 + l) * 4];
        S[4*r4]   += v.x; S[4*r4+1] += v.y; S[4*r4+2] += v.z; S[4*r4+3] += v.w;
      }
    }
    // recombine complex: P = cos rows (even kyc), Q = -sin rows (odd kyc)
    const int c = l & 1;
    #pragma unroll
    for (int q = 0; q < 8; ++q) {
      int r0 = 2 * q;
      float T = __shfl_xor(S[r0 + 1], 1, 64);
      float val = c ? (S[r0] + T) : (S[r0] - T);
      int kyp_loc = ((r0 & 3) >> 1) + 4 * (r0 >> 2) + 2 * (l >> 5);
      F[((size_t)bi * 32 + mt * 16 + kyp_loc) * 32 + (l & 31)] = val;
    }
  }
}

// ---------------- Stage 3: complex channel mix -------------------------
__global__ __launch_bounds__(512) void mix_kernel(const float* __restrict__ F,
    const float* __restrict__ w1r, const float* __restrict__ w1i,
    const float* __restrict__ w2r, const float* __restrict__ w2i,
    float* __restrict__ G) {
  const int tid = threadIdx.x;
  const int b = blockIdx.x >> 5;   // blockIdx = b*CO + o
  const int o = blockIdx.x & 31;
  const int kyp = tid >> 4;
  const int kx = tid & 15;
  const bool top = kyp < 16;
  const int m = top ? kyp : (kyp - 16);
  const float* wr = top ? w1r : w2r;
  const float* wi = top ? w1i : w2i;
  float gr = 0.f, gi = 0.f;
  for (int i = 0; i < CI; ++i) {
    float2 f = *(const float2*)&F[(((size_t)b * CI + i) * KYp + kyp) * (HM * 2) + kx * 2];
    size_t wo = (((size_t)i * CO + o) * HM + m) * HM + kx;
    float wrv = wr[wo], wiv = wi[wo];
    gr = fmaf(f.x, wrv, gr); gr = fmaf(-f.y, wiv, gr);
    gi = fmaf(f.x, wiv, gi); gi = fmaf(f.y, wrv, gi);
  }
  size_t go = ((size_t)blockIdx.x) * (KYp * HM * 2) + (kyp * HM + kx) * 2;
  *(float2*)(G + go) = make_float2(gr, gi);
}

// ---------------- Stage 4: inverse DFT over ky -> 512 rows -------------
__global__ __launch_bounds__(256) void t1_kernel(const float* __restrict__ G,
                                                 float* __restrict__ gws) {
  __shared__ float Gs[KYp * HM * 2];  // 4 KB
  __shared__ float ct[512];
  __shared__ float st[512];
  const int tid = threadIdx.x;
  const int blk = blockIdx.x;
  const int tile = blk & 31;
  const int bo = blk >> 5;
  #pragma unroll
  for (int j = 0; j < 2; ++j) {
    int t = tid + j * 256;
    float ang = TWO_PI * (float)t / 512.0f;
    ct[t] = cosf(ang);
    st[t] = sinf(ang);
  }
  ((float4*)Gs)[tid] = ((const float4*)(G + (size_t)bo * (KYp * HM * 2)))[tid];
  __syncthreads();
  const int r = tid >> 4;
  const int kx = tid & 15;
  const int h = tile * 16 + r;
  float gr = 0.f, gi = 0.f;
  #pragma unroll
  for (int kyp = 0; kyp < 32; ++kyp) {
    const int ky = (kyp < 16) ? kyp : (kyp + 480);
    const int t = (ky * h) & 511;
    float cc = ct[t], ss = st[t];
    float2 Gv = *(const float2*)&Gs[(kyp * HM + kx) * 2];
    // (Gr + i Gi) * (cc + i ss)
    gr = fmaf(Gv.x, cc, gr); gr = fmaf(-Gv.y, ss, gr);
    gi = fmaf(Gv.x, ss, gi); gi = fmaf(Gv.y, cc, gi);
  }
  size_t o = ((size_t)bo * Hh + h) * (HM * 2) + kx * 2;
  *(float2*)(gws + o) = make_float2(gr, gi);
}

// ---------------- Stage 5: inverse DFT over kx -> 512 cols, +bias ------
__global__ __launch_bounds__(256) void t2_kernel(const float* __restrict__ gws,
                                                 const float* __restrict__ bias,
                                                 float* __restrict__ y) {
  const int tid = threadIdx.x;
  const int blk = blockIdx.x;
  const int q = blk & 3;       // row quarter (128 rows)
  const int bo = blk >> 2;     // b*CO + o
  const int o = bo & 31;
  const float bv = bias[o];
  const float inv = 1.0f / 262144.0f;  // 1/(H*W)
  const int w0 = tid;          // columns w0 and w0+256
  float C[15], S[15];
  #pragma unroll
  for (int k = 0; k < 15; ++k) {
    int t = ((k + 1) * w0) & 511;
    float ang = TWO_PI * (float)t / 512.0f;
    float sv, cv;
    sincosf(ang, &sv, &cv);
    C[k] = 2.0f * cv;   // fold the hermitian x2 into the twiddle
    S[k] = 2.0f * sv;
  }
  const float* grow = gws + ((size_t)bo * Hh + q * 128) * (HM * 2);
  float* yrow = y + ((size_t)bo * Hh + q * 128) * Ww;
  for (int r = 0; r < 128; ++r) {
    float qa[32];
    const float4* gp = (const float4*)(grow + r * (HM * 2));
    #pragma unroll
    for (int j = 0; j < 8; ++j) ((float4*)qa)[j] = gp[j];
    // even/odd-k split: col w0 gets E+O, col w0+256 gets E-O (cos(th+k*pi))
    float E = qa[0];       // DC: real part only (pocketfft c2r semantics)
    float O = 0.f, E2 = 0.f, O2 = 0.f;
    #pragma unroll
    for (int k = 1; k <= 15; ++k) {
      float tv = fmaf(-qa[2 * k + 1], S[k - 1], qa[2 * k] * C[k - 1]);
      if (k & 1) { if (k & 2) O2 += tv; else O += tv; }
      else       { if (k & 2) E2 += tv; else E += tv; }
    }
    float Ee = E + E2, Oo = O + O2;
    yrow[r * Ww + w0]       = fmaf(inv, Ee + Oo, bv);
    yrow[r * Ww + w0 + 256] = fmaf(inv, Ee - Oo, bv);
  }
}

extern "C" void kernel_launch(void* const* d_in, const int* in_sizes, int n_in,
                              void* d_out, int out_size, void* d_ws, size_t ws_size,
                              hipStream_t stream) {
  const float* x    = (const float*)d_in[0];
  const float* w1r  = (const float*)d_in[1];
  const float* w1i  = (const float*)d_in[2];
  const float* w2r  = (const float*)d_in[3];
  const float* w2i  = (const float*)d_in[4];
  const float* bias = (const float*)d_in[5];
  float* y  = (float*)d_out;
  float* ws = (float*)d_ws;
  float* F   = ws + F_OFF;
  float* G   = ws + G_OFF;
  float* g   = ws + g_OFF;
  float* E   = ws + g_OFF;          // 32 KB (dead before t1)
  float* E2c = ws + g_OFF + 8192;   // 64 KB (dead before t1)

  hipLaunchKernelGGL(e_init_kernel, dim3(192), dim3(256), 0, stream, E);
  // ABLATION (round 6): fwd launched TWICE, byte-identical code otherwise.
  // fwd is idempotent (reads x + E tables, overwrites F unconditionally),
  // so total_r6 - total_r5 = fwd duration, exactly.
  hipLaunchKernelGGL(fwd_kernel,  dim3(Bb * CI), dim3(512), 0, stream, x, E, E2c, F);
  hipLaunchKernelGGL(fwd_kernel,  dim3(Bb * CI), dim3(512), 0, stream, x, E, E2c, F);
  hipLaunchKernelGGL(mix_kernel, dim3(Bb * CO), dim3(512), 0, stream, F,
                     w1r, w1i, w2r, w2i, G);
  hipLaunchKernelGGL(t1_kernel,  dim3(Bb * CO * 32), dim3(256), 0, stream, G, g);
  hipLaunchKernelGGL(t2_kernel,  dim3(Bb * CO * 4),  dim3(256), 0, stream, g, bias, y);
}

// Round 7
// 179.316 us; speedup vs baseline: 1.3437x; 1.3437x over previous
//
#include <hip/hip_runtime.h>
#include <math.h>

#define Hh 512
#define Ww 512
#define Bb 8
#define CI 32
#define CO 32
#define HM 16   // kx modes kept
#define KYp 32  // packed ky modes (0..15 and 496..511)

static constexpr float TWO_PI = 6.28318530717958647692f;

// workspace layout (float offsets)
#define F_OFF  4194304u   // [B*CI][32][16][2] = 262,144 floats
#define g_OFF  4718592u   // E tables live here (only fwd reads them)
// E  (bf16 phase-1 DFT frags, 32 KB)  at g_OFF
// E2c (bf16 phase-2 DFT frags, 64 KB) at g_OFF + 8192

using short8 = __attribute__((ext_vector_type(8))) short;
using f32x16 = __attribute__((ext_vector_type(16))) float;

__device__ inline unsigned short bf16_rn(float f) {
  unsigned u = __float_as_uint(f);
  u += 0x7FFFu + ((u >> 16) & 1u);
  return (unsigned short)(u >> 16);
}

// exact split of 4 floats into hi(bf16-trunc) + lo(residual as bf16)
__device__ inline void split4(float4 v, uint2& h2, uint2& l2) {
  unsigned u0 = __float_as_uint(v.x), u1 = __float_as_uint(v.y);
  unsigned u2 = __float_as_uint(v.z), u3 = __float_as_uint(v.w);
  float f0 = v.x - __uint_as_float(u0 & 0xFFFF0000u);
  float f1 = v.y - __uint_as_float(u1 & 0xFFFF0000u);
  float f2 = v.z - __uint_as_float(u2 & 0xFFFF0000u);
  float f3 = v.w - __uint_as_float(u3 & 0xFFFF0000u);
  h2.x = (u1 & 0xFFFF0000u) | (u0 >> 16);
  h2.y = (u3 & 0xFFFF0000u) | (u2 >> 16);
  l2.x = (__float_as_uint(f1) & 0xFFFF0000u) | (__float_as_uint(f0) >> 16);
  l2.y = (__float_as_uint(f3) & 0xFFFF0000u) | (__float_as_uint(f2) >> 16);
}

// --------- E init: both DFT-matrix fragment tables -----------------------
__global__ __launch_bounds__(256) void e_init_kernel(float* __restrict__ Ef) {
  unsigned short* E = (unsigned short*)Ef;
  int idx = blockIdx.x * 256 + threadIdx.x;   // 0..49151
  if (idx < 16384) {
    int kk = idx >> 9;
    int l = (idx >> 3) & 63;
    int j = idx & 7;
    int k = kk * 16 + 8 * (l >> 5) + j;
    int col = l & 31;
    int kx = col >> 1;
    int t = (kx * k) & 511;
    float sv, cv;
    sincosf(TWO_PI * (float)t / 512.0f, &sv, &cv);
    E[idx] = bf16_rn((col & 1) ? -sv : cv);
  } else {
    int idx2 = idx - 16384;
    int mt = idx2 >> 14;
    int rem = idx2 & 16383;
    int kk = rem >> 9;
    int l = (rem >> 3) & 63;
    int j = rem & 7;
    int h = kk * 16 + 8 * (l >> 5) + j;
    int kyc = l & 31;
    int kyp = mt * 16 + (kyc >> 1);
    int ky = (kyp < 16) ? kyp : (kyp + 480);
    int t = (ky * h) & 511;
    float sv, cv;
    sincosf(TWO_PI * (float)t / 512.0f, &sv, &cv);
    E[idx] = bf16_rn((kyc & 1) ? -sv : cv);
  }
}

// ---------------- fwd: x image -> F (unchanged from round 5) -------------
__global__ __launch_bounds__(512) void fwd_kernel(const float* __restrict__ x,
                                                  const float* __restrict__ Ef,
                                                  const float* __restrict__ E2f,
                                                  float* __restrict__ F) {
  __shared__ char lds[135168];
  short* E2l = (short*)lds;                 // [mt 2][kk 32][64][8]  64 KB
  short* Xh  = (short*)(lds + 65536);       // [kc 32][64][8]        32 KB
  short* Xl  = (short*)(lds + 98304);       //                       32 KB
  float* red = (float*)(lds + 65536);       // alias Xh
  short* Ah  = (short*)(lds + 131072);      // [kc2 2][64][8]         2 KB
  short* Al  = (short*)(lds + 133120);      //                        2 KB
  float* Pbuf = (float*)(lds + 65536);      // final reduce (alias)

  const int tid = threadIdx.x;
  const int l = tid & 63;
  const int wid = tid >> 6;
  const int bi = blockIdx.x;
  const float* xb = x + (size_t)bi * (Hh * Ww);

  {
    const float4* Eg = (const float4*)E2f;
    float4* El4 = (float4*)E2l;
    #pragma unroll
    for (int j = 0; j < 8; ++j) El4[tid + j * 512] = Eg[tid + j * 512];
  }
  short8 e1[4];
  {
    const short* Eg = (const short*)Ef;
    #pragma unroll
    for (int c = 0; c < 4; ++c)
      e1[c] = *(const short8*)(Eg + ((size_t)(4 * wid + c) * 64 + l) * 8);
  }

  const int hb = (l >> 1) & 1;
  const int jfr = 4 * (l & 1);
  const int kc0 = l >> 2;

  float4 rv[8];
  #pragma unroll
  for (int j = 0; j < 4; ++j) {
    const float* rowp = xb + (size_t)(wid * 4 + j) * 512;
    rv[2 * j]     = *(const float4*)(rowp + 4 * l);
    rv[2 * j + 1] = *(const float4*)(rowp + 256 + 4 * l);
  }

  f32x16 acc1 = {0.f,0.f,0.f,0.f,0.f,0.f,0.f,0.f,0.f,0.f,0.f,0.f,0.f,0.f,0.f,0.f};
  f32x16 acc2 = {0.f,0.f,0.f,0.f,0.f,0.f,0.f,0.f,0.f,0.f,0.f,0.f,0.f,0.f,0.f,0.f};

  const int mt2 = wid & 1, kc2w = (wid >> 1) & 1, part2 = wid >> 2;

  for (int s = 0; s < 16; ++s) {
    if (s > 0) {
      short8 a2 = *(const short8*)&E2l[((mt2 * 32 + ((s - 1) * 2 + kc2w)) * 64 + l) * 8];
      short8 b2 = part2 ? *(const short8*)&Al[(kc2w * 64 + l) * 8]
                        : *(const short8*)&Ah[(kc2w * 64 + l) * 8];
      acc2 = __builtin_amdgcn_mfma_f32_32x32x16_bf16(a2, b2, acc2, 0, 0, 0);
    }
    #pragma unroll
    for (int j = 0; j < 4; ++j) {
      #pragma unroll
      for (int hf = 0; hf < 2; ++hf) {
        int kc = hf * 16 + kc0;
        int lanep = (wid * 4 + j) + 32 * hb;
        int off = ((kc * 64) + (lanep ^ (kc & 7))) * 8 + jfr;
        uint2 h2, l2;
        split4(rv[2 * j + hf], h2, l2);
        *(uint2*)&Xh[off] = h2;
        *(uint2*)&Xl[off] = l2;
      }
    }
    if (s < 15) {
      #pragma unroll
      for (int j = 0; j < 4; ++j) {
        const float* rowp = xb + (size_t)((s + 1) * 32 + wid * 4 + j) * 512;
        rv[2 * j]     = *(const float4*)(rowp + 4 * l);
        rv[2 * j + 1] = *(const float4*)(rowp + 256 + 4 * l);
      }
    }
    __syncthreads();
    #pragma unroll
    for (int c = 0; c < 4; ++c) {
      int kc = 4 * wid + c;
      int slot = ((kc * 64) + (l ^ (kc & 7))) * 8;
      short8 hi = *(const short8*)&Xh[slot];
      short8 lo = *(const short8*)&Xl[slot];
      acc1 = __builtin_amdgcn_mfma_f32_32x32x16_bf16(hi, e1[c], acc1, 0, 0, 0);
      acc1 = __builtin_amdgcn_mfma_f32_32x32x16_bf16(lo, e1[c], acc1, 0, 0, 0);
    }
    __syncthreads();
    #pragma unroll
    for (int q = 0; q < 4; ++q)
      *(float4*)&red[((wid * 4 + q) * 64 + l) * 4] =
          make_float4(acc1[4*q], acc1[4*q+1], acc1[4*q+2], acc1[4*q+3]);
    #pragma unroll
    for (int r = 0; r < 16; ++r) acc1[r] = 0.f;
    __syncthreads();
    if (wid < 4) {
      const int q = wid;
      float4 sum = make_float4(0.f, 0.f, 0.f, 0.f);
      #pragma unroll
      for (int w = 0; w < 8; ++w) {
        float4 v = *(const float4*)&red[((w * 4 + q) * 64 + l) * 4];
        sum.x += v.x; sum.y += v.y; sum.z += v.z; sum.w += v.w;
      }
      uint2 h2, l2;
      split4(sum, h2, l2);
      int off = ((q >> 1) * 64 + ((l & 31) + 32 * (q & 1))) * 8 + 4 * (l >> 5);
      *(uint2*)&Ah[off] = h2;
      *(uint2*)&Al[off] = l2;
    }
    __syncthreads();
  }
  {
    short8 a2 = *(const short8*)&E2l[((mt2 * 32 + (15 * 2 + kc2w)) * 64 + l) * 8];
    short8 b2 = part2 ? *(const short8*)&Al[(kc2w * 64 + l) * 8]
                      : *(const short8*)&Ah[(kc2w * 64 + l) * 8];
    acc2 = __builtin_amdgcn_mfma_f32_32x32x16_bf16(a2, b2, acc2, 0, 0, 0);
  }
  #pragma unroll
  for (int r4 = 0; r4 < 4; ++r4)
    *(float4*)&Pbuf[((wid * 4 + r4) * 64 + l) * 4] =
        make_float4(acc2[4*r4], acc2[4*r4+1], acc2[4*r4+2], acc2[4*r4+3]);
  __syncthreads();

  if (wid < 2) {
    const int mt = wid;
    float S[16];
    #pragma unroll
    for (int r = 0; r < 16; ++r) S[r] = 0.f;
    #pragma unroll
    for (int p = 0; p < 4; ++p) {
      #pragma unroll
      for (int r4 = 0; r4 < 4; ++r4) {
        float4 v = *(const float4*)&Pbuf[(((mt + 2 * p) * 4 + r4) * 64 + l) * 4];
        S[4*r4]   += v.x; S[4*r4+1] += v.y; S[4*r4+2] += v.z; S[4*r4+3] += v.w;
      }
    }
    const int c = l & 1;
    #pragma unroll
    for (int q = 0; q < 8; ++q) {
      int r0 = 2 * q;
      float T = __shfl_xor(S[r0 + 1], 1, 64);
      float val = c ? (S[r0] + T) : (S[r0] - T);
      int kyp_loc = ((r0 & 3) >> 1) + 4 * (r0 >> 2) + 2 * (l >> 5);
      F[((size_t)bi * 32 + mt * 16 + kyp_loc) * 32 + (l & 31)] = val;
    }
  }
}

// ---------------- bwd: F -> y (fuses mix + t1 + t2) ----------------------
// One block per (b,o), 512 threads. LDS: ct/st 4 KB + G 4 KB + g 64 KB.
__global__ __launch_bounds__(512) void bwd_kernel(const float* __restrict__ F,
    const float* __restrict__ w1r, const float* __restrict__ w1i,
    const float* __restrict__ w2r, const float* __restrict__ w2i,
    const float* __restrict__ bias, float* __restrict__ y) {
  __shared__ float ct[512];
  __shared__ float st[512];
  __shared__ float Gs[KYp * HM * 2];     // [kyp][kx][2]  4 KB
  __shared__ float gs[Hh * HM * 2];      // [h][kx][2]   64 KB

  const int tid = threadIdx.x;
  const int b = blockIdx.x >> 5;
  const int o = blockIdx.x & 31;

  // twiddle table (1 sincosf/thread)
  {
    float sv, cv;
    sincosf(TWO_PI * (float)tid / 512.0f, &sv, &cv);
    ct[tid] = cv;
    st[tid] = sv;
  }

  // ---- mix: one complex G mode per thread ----
  {
    const int kyp = tid >> 4;
    const int kx = tid & 15;
    const bool top = kyp < 16;
    const int m = top ? kyp : (kyp - 16);
    const float* wr = top ? w1r : w2r;
    const float* wi = top ? w1i : w2i;
    float gr = 0.f, gi = 0.f;
    for (int i = 0; i < CI; ++i) {
      float2 f = *(const float2*)&F[(((size_t)b * CI + i) * KYp + kyp) * (HM * 2) + kx * 2];
      size_t wo = (((size_t)i * CO + o) * HM + m) * HM + kx;
      float wrv = wr[wo], wiv = wi[wo];
      gr = fmaf(f.x, wrv, gr); gr = fmaf(-f.y, wiv, gr);
      gi = fmaf(f.x, wiv, gi); gi = fmaf(f.y, wrv, gi);
    }
    Gs[(kyp * HM + kx) * 2]     = gr;
    Gs[(kyp * HM + kx) * 2 + 1] = gi;
  }
  __syncthreads();

  // ---- t1: thread = h row; accumulate all 16 kx over 32 kyp ----
  {
    const int h = tid;
    float gr[16], gi[16];
    #pragma unroll
    for (int kx = 0; kx < 16; ++kx) { gr[kx] = 0.f; gi[kx] = 0.f; }
    #pragma unroll 4
    for (int kyp = 0; kyp < 32; ++kyp) {
      const int ky = (kyp < 16) ? kyp : (kyp + 480);
      const int t = (ky * h) & 511;
      const float cc = ct[t], ss = st[t];
      #pragma unroll
      for (int kx = 0; kx < 16; ++kx) {
        float Gr = Gs[(kyp * HM + kx) * 2];
        float Gi = Gs[(kyp * HM + kx) * 2 + 1];
        gr[kx] = fmaf(Gr, cc, gr[kx]); gr[kx] = fmaf(-Gi, ss, gr[kx]);
        gi[kx] = fmaf(Gr, ss, gi[kx]); gi[kx] = fmaf(Gi, cc, gi[kx]);
      }
    }
    #pragma unroll
    for (int kx = 0; kx < 16; ++kx) {
      gs[(h * HM + kx) * 2]     = gr[kx];
      gs[(h * HM + kx) * 2 + 1] = gi[kx];
    }
  }
  __syncthreads();

  // ---- t2: thread = (col pair w0/w0+256, row half); 256 rows each ----
  {
    const int w0 = tid & 255;
    const int rh = tid >> 8;
    const float bv = bias[o];
    const float inv = 1.0f / 262144.0f;
    float C[15], S[15];
    #pragma unroll
    for (int k = 0; k < 15; ++k) {
      int t = ((k + 1) * w0) & 511;
      float sv, cv;
      sincosf(TWO_PI * (float)t / 512.0f, &sv, &cv);
      C[k] = 2.0f * cv;
      S[k] = 2.0f * sv;
    }
    float* yrow = y + ((size_t)blockIdx.x * Hh + rh * 256) * Ww;
    const float* grow = gs + (rh * 256) * (HM * 2);
    for (int r = 0; r < 256; ++r) {
      float qa[32];
      const float4* gp = (const float4*)(grow + r * (HM * 2));
      #pragma unroll
      for (int j = 0; j < 8; ++j) ((float4*)qa)[j] = gp[j];
      float E = qa[0];       // DC: real part only
      float O = 0.f, E2 = 0.f, O2 = 0.f;
      #pragma unroll
      for (int k = 1; k <= 15; ++k) {
        float tv = fmaf(-qa[2 * k + 1], S[k - 1], qa[2 * k] * C[k - 1]);
        if (k & 1) { if (k & 2) O2 += tv; else O += tv; }
        else       { if (k & 2) E2 += tv; else E += tv; }
      }
      float Ee = E + E2, Oo = O + O2;
      yrow[r * Ww + w0]       = fmaf(inv, Ee + Oo, bv);
      yrow[r * Ww + w0 + 256] = fmaf(inv, Ee - Oo, bv);
    }
  }
}

extern "C" void kernel_launch(void* const* d_in, const int* in_sizes, int n_in,
                              void* d_out, int out_size, void* d_ws, size_t ws_size,
                              hipStream_t stream) {
  const float* x    = (const float*)d_in[0];
  const float* w1r  = (const float*)d_in[1];
  const float* w1i  = (const float*)d_in[2];
  const float* w2r  = (const float*)d_in[3];
  const float* w2i  = (const float*)d_in[4];
  const float* bias = (const float*)d_in[5];
  float* y  = (float*)d_out;
  float* ws = (float*)d_ws;
  float* F   = ws + F_OFF;
  float* E   = ws + g_OFF;          // 32 KB
  float* E2c = ws + g_OFF + 8192;   // 64 KB

  hipLaunchKernelGGL(e_init_kernel, dim3(192), dim3(256), 0, stream, E);
  hipLaunchKernelGGL(fwd_kernel, dim3(Bb * CI), dim3(512), 0, stream, x, E, E2c, F);
  hipLaunchKernelGGL(bwd_kernel, dim3(Bb * CO), dim3(512), 0, stream, F,
                     w1r, w1i, w2r, w2i, bias, y);
}

// Round 8
// 151.922 us; speedup vs baseline: 1.5860x; 1.1803x over previous
//
#include <hip/hip_runtime.h>
#include <math.h>

#define Hh 512
#define Ww 512
#define Bb 8
#define CI 32
#define CO 32
#define HM 16   // kx modes kept
#define KYp 32  // packed ky modes (0..15 and 496..511)

static constexpr float TWO_PI = 6.28318530717958647692f;

// workspace layout (float offsets)
#define F_OFF  4194304u   // [B*CI][32][16][2] = 262,144 floats
#define g_OFF  4718592u   // E tables live here (only fwd/bwd read them)
// E   (bf16 phase-1 DFT frags, 32 KB)  at g_OFF
// E2c (bf16 phase-2 DFT frags, 64 KB)  at g_OFF + 8192
// T2f (bf16 t2 B-frags,        32 KB)  at g_OFF + 24576

using short8 = __attribute__((ext_vector_type(8))) short;
using f32x16 = __attribute__((ext_vector_type(16))) float;

__device__ inline unsigned short bf16_rn(float f) {
  unsigned u = __float_as_uint(f);
  u += 0x7FFFu + ((u >> 16) & 1u);
  return (unsigned short)(u >> 16);
}

// exact split of 4 floats into hi(bf16-trunc) + lo(residual as bf16)
__device__ inline void split4(float4 v, uint2& h2, uint2& l2) {
  unsigned u0 = __float_as_uint(v.x), u1 = __float_as_uint(v.y);
  unsigned u2 = __float_as_uint(v.z), u3 = __float_as_uint(v.w);
  float f0 = v.x - __uint_as_float(u0 & 0xFFFF0000u);
  float f1 = v.y - __uint_as_float(u1 & 0xFFFF0000u);
  float f2 = v.z - __uint_as_float(u2 & 0xFFFF0000u);
  float f3 = v.w - __uint_as_float(u3 & 0xFFFF0000u);
  h2.x = (u1 & 0xFFFF0000u) | (u0 >> 16);
  h2.y = (u3 & 0xFFFF0000u) | (u2 >> 16);
  l2.x = (__float_as_uint(f1) & 0xFFFF0000u) | (__float_as_uint(f0) >> 16);
  l2.y = (__float_as_uint(f3) & 0xFFFF0000u) | (__float_as_uint(f2) >> 16);
}

// --------- E init: all DFT-matrix fragment tables ------------------------
// idx 0..16383: E1; 16384..49151: E2c; 49152..65535: T2frag
__global__ __launch_bounds__(256) void e_init_kernel(float* __restrict__ Ef) {
  unsigned short* E = (unsigned short*)Ef;
  int idx = blockIdx.x * 256 + threadIdx.x;   // 0..65535
  if (idx < 16384) {
    int kk = idx >> 9;
    int l = (idx >> 3) & 63;
    int j = idx & 7;
    int k = kk * 16 + 8 * (l >> 5) + j;
    int col = l & 31;
    int kx = col >> 1;
    int t = (kx * k) & 511;
    float sv, cv;
    sincosf(TWO_PI * (float)t / 512.0f, &sv, &cv);
    E[idx] = bf16_rn((col & 1) ? -sv : cv);
  } else if (idx < 49152) {
    int idx2 = idx - 16384;
    int mt = idx2 >> 14;
    int rem = idx2 & 16383;
    int kk = rem >> 9;
    int l = (rem >> 3) & 63;
    int j = rem & 7;
    int h = kk * 16 + 8 * (l >> 5) + j;
    int kyc = l & 31;
    int kyp = mt * 16 + (kyc >> 1);
    int ky = (kyp < 16) ? kyp : (kyp + 480);
    int t = (ky * h) & 511;
    float sv, cv;
    sincosf(TWO_PI * (float)t / 512.0f, &sv, &cv);
    E[idx] = bf16_rn((kyc & 1) ? -sv : cv);
  } else {
    // T2frag[ntile 16][s 2][lane 64][j 8]:
    //   K = s*16 + 8*(l>>5) + j = 2k+c ; w = ntile*32 + (l&31)
    //   val = inv * wk * (c ? -sin : cos)(2pi k w/512), wk = (k==0?1:2)
    int rem = idx - 49152;                 // 0..16383
    int ntile = rem >> 10;
    int s = (rem >> 9) & 1;
    int l = (rem >> 3) & 63;
    int j = rem & 7;
    int K = s * 16 + 8 * (l >> 5) + j;
    int k = K >> 1, c = K & 1;
    int w = ntile * 32 + (l & 31);
    int t = (k * w) & 511;
    float sv, cv;
    sincosf(TWO_PI * (float)t / 512.0f, &sv, &cv);
    float wk = (k == 0) ? 1.0f : 2.0f;
    float inv = 1.0f / 262144.0f;
    E[idx] = bf16_rn(inv * wk * (c ? -sv : cv));
  }
}

// ---------------- fwd: x image -> F (unchanged from round 5) -------------
__global__ __launch_bounds__(512) void fwd_kernel(const float* __restrict__ x,
                                                  const float* __restrict__ Ef,
                                                  const float* __restrict__ E2f,
                                                  float* __restrict__ F) {
  __shared__ char lds[135168];
  short* E2l = (short*)lds;                 // [mt 2][kk 32][64][8]  64 KB
  short* Xh  = (short*)(lds + 65536);       // [kc 32][64][8]        32 KB
  short* Xl  = (short*)(lds + 98304);       //                       32 KB
  float* red = (float*)(lds + 65536);       // alias Xh
  short* Ah  = (short*)(lds + 131072);      // [kc2 2][64][8]         2 KB
  short* Al  = (short*)(lds + 133120);      //                        2 KB
  float* Pbuf = (float*)(lds + 65536);      // final reduce (alias)

  const int tid = threadIdx.x;
  const int l = tid & 63;
  const int wid = tid >> 6;
  const int bi = blockIdx.x;
  const float* xb = x + (size_t)bi * (Hh * Ww);

  {
    const float4* Eg = (const float4*)E2f;
    float4* El4 = (float4*)E2l;
    #pragma unroll
    for (int j = 0; j < 8; ++j) El4[tid + j * 512] = Eg[tid + j * 512];
  }
  short8 e1[4];
  {
    const short* Eg = (const short*)Ef;
    #pragma unroll
    for (int c = 0; c < 4; ++c)
      e1[c] = *(const short8*)(Eg + ((size_t)(4 * wid + c) * 64 + l) * 8);
  }

  const int hb = (l >> 1) & 1;
  const int jfr = 4 * (l & 1);
  const int kc0 = l >> 2;

  float4 rv[8];
  #pragma unroll
  for (int j = 0; j < 4; ++j) {
    const float* rowp = xb + (size_t)(wid * 4 + j) * 512;
    rv[2 * j]     = *(const float4*)(rowp + 4 * l);
    rv[2 * j + 1] = *(const float4*)(rowp + 256 + 4 * l);
  }

  f32x16 acc1 = {0.f,0.f,0.f,0.f,0.f,0.f,0.f,0.f,0.f,0.f,0.f,0.f,0.f,0.f,0.f,0.f};
  f32x16 acc2 = {0.f,0.f,0.f,0.f,0.f,0.f,0.f,0.f,0.f,0.f,0.f,0.f,0.f,0.f,0.f,0.f};

  const int mt2 = wid & 1, kc2w = (wid >> 1) & 1, part2 = wid >> 2;

  for (int s = 0; s < 16; ++s) {
    if (s > 0) {
      short8 a2 = *(const short8*)&E2l[((mt2 * 32 + ((s - 1) * 2 + kc2w)) * 64 + l) * 8];
      short8 b2 = part2 ? *(const short8*)&Al[(kc2w * 64 + l) * 8]
                        : *(const short8*)&Ah[(kc2w * 64 + l) * 8];
      acc2 = __builtin_amdgcn_mfma_f32_32x32x16_bf16(a2, b2, acc2, 0, 0, 0);
    }
    #pragma unroll
    for (int j = 0; j < 4; ++j) {
      #pragma unroll
      for (int hf = 0; hf < 2; ++hf) {
        int kc = hf * 16 + kc0;
        int lanep = (wid * 4 + j) + 32 * hb;
        int off = ((kc * 64) + (lanep ^ (kc & 7))) * 8 + jfr;
        uint2 h2, l2;
        split4(rv[2 * j + hf], h2, l2);
        *(uint2*)&Xh[off] = h2;
        *(uint2*)&Xl[off] = l2;
      }
    }
    if (s < 15) {
      #pragma unroll
      for (int j = 0; j < 4; ++j) {
        const float* rowp = xb + (size_t)((s + 1) * 32 + wid * 4 + j) * 512;
        rv[2 * j]     = *(const float4*)(rowp + 4 * l);
        rv[2 * j + 1] = *(const float4*)(rowp + 256 + 4 * l);
      }
    }
    __syncthreads();
    #pragma unroll
    for (int c = 0; c < 4; ++c) {
      int kc = 4 * wid + c;
      int slot = ((kc * 64) + (l ^ (kc & 7))) * 8;
      short8 hi = *(const short8*)&Xh[slot];
      short8 lo = *(const short8*)&Xl[slot];
      acc1 = __builtin_amdgcn_mfma_f32_32x32x16_bf16(hi, e1[c], acc1, 0, 0, 0);
      acc1 = __builtin_amdgcn_mfma_f32_32x32x16_bf16(lo, e1[c], acc1, 0, 0, 0);
    }
    __syncthreads();
    #pragma unroll
    for (int q = 0; q < 4; ++q)
      *(float4*)&red[((wid * 4 + q) * 64 + l) * 4] =
          make_float4(acc1[4*q], acc1[4*q+1], acc1[4*q+2], acc1[4*q+3]);
    #pragma unroll
    for (int r = 0; r < 16; ++r) acc1[r] = 0.f;
    __syncthreads();
    if (wid < 4) {
      const int q = wid;
      float4 sum = make_float4(0.f, 0.f, 0.f, 0.f);
      #pragma unroll
      for (int w = 0; w < 8; ++w) {
        float4 v = *(const float4*)&red[((w * 4 + q) * 64 + l) * 4];
        sum.x += v.x; sum.y += v.y; sum.z += v.z; sum.w += v.w;
      }
      uint2 h2, l2;
      split4(sum, h2, l2);
      int off = ((q >> 1) * 64 + ((l & 31) + 32 * (q & 1))) * 8 + 4 * (l >> 5);
      *(uint2*)&Ah[off] = h2;
      *(uint2*)&Al[off] = l2;
    }
    __syncthreads();
  }
  {
    short8 a2 = *(const short8*)&E2l[((mt2 * 32 + (15 * 2 + kc2w)) * 64 + l) * 8];
    short8 b2 = part2 ? *(const short8*)&Al[(kc2w * 64 + l) * 8]
                      : *(const short8*)&Ah[(kc2w * 64 + l) * 8];
    acc2 = __builtin_amdgcn_mfma_f32_32x32x16_bf16(a2, b2, acc2, 0, 0, 0);
  }
  #pragma unroll
  for (int r4 = 0; r4 < 4; ++r4)
    *(float4*)&Pbuf[((wid * 4 + r4) * 64 + l) * 4] =
        make_float4(acc2[4*r4], acc2[4*r4+1], acc2[4*r4+2], acc2[4*r4+3]);
  __syncthreads();

  if (wid < 2) {
    const int mt = wid;
    float S[16];
    #pragma unroll
    for (int r = 0; r < 16; ++r) S[r] = 0.f;
    #pragma unroll
    for (int p = 0; p < 4; ++p) {
      #pragma unroll
      for (int r4 = 0; r4 < 4; ++r4) {
        float4 v = *(const float4*)&Pbuf[(((mt + 2 * p) * 4 + r4) * 64 + l) * 4];
        S[4*r4]   += v.x; S[4*r4+1] += v.y; S[4*r4+2] += v.z; S[4*r4+3] += v.w;
      }
    }
    const int c = l & 1;
    #pragma unroll
    for (int q = 0; q < 8; ++q) {
      int r0 = 2 * q;
      float T = __shfl_xor(S[r0 + 1], 1, 64);
      float val = c ? (S[r0] + T) : (S[r0] - T);
      int kyp_loc = ((r0 & 3) >> 1) + 4 * (r0 >> 2) + 2 * (l >> 5);
      F[((size_t)bi * 32 + mt * 16 + kyp_loc) * 32 + (l & 31)] = val;
    }
  }
}

// ---------------- bwd: F -> y (mix + t1 scalar, t2 via MFMA) -------------
// One block per (b,o), 512 threads. LDS 104 KB:
//   T2l 32 KB | ct 2 KB | st 2 KB | Gs 4 KB | Ah 32 KB | Al 32 KB
__global__ __launch_bounds__(512) void bwd_kernel(const float* __restrict__ F,
    const float* __restrict__ w1r, const float* __restrict__ w1i,
    const float* __restrict__ w2r, const float* __restrict__ w2i,
    const float* __restrict__ bias, const float* __restrict__ T2f,
    float* __restrict__ y) {
  __shared__ char lds[106496];
  short* T2l = (short*)lds;                 // [ntile 16][s 2][64][8]  32 KB
  float* ct  = (float*)(lds + 32768);       // 2 KB
  float* st  = (float*)(lds + 34816);       // 2 KB
  float* Gs  = (float*)(lds + 36864);       // [kyp 32][kx 16][2]      4 KB
  short* Ah  = (short*)(lds + 40960);       // [mtile 16][s 2][64][8] 32 KB
  short* Al  = (short*)(lds + 73728);       // 32 KB

  const int tid = threadIdx.x;
  const int l = tid & 63;
  const int wid = tid >> 6;
  const int b = blockIdx.x >> 5;
  const int o = blockIdx.x & 31;
  const float bv = bias[o];

  // stage T2 fragments (32 KB), coalesced
  {
    const float4* Tg = (const float4*)T2f;
    float4* Tl4 = (float4*)T2l;
    #pragma unroll
    for (int j = 0; j < 4; ++j) Tl4[tid + j * 512] = Tg[tid + j * 512];
  }
  // twiddle table (1 sincosf/thread)
  {
    float sv, cv;
    sincosf(TWO_PI * (float)tid / 512.0f, &sv, &cv);
    ct[tid] = cv;
    st[tid] = sv;
  }

  // ---- mix: one complex G mode per thread ----
  {
    const int kyp = tid >> 4;
    const int kx = tid & 15;
    const bool top = kyp < 16;
    const int m = top ? kyp : (kyp - 16);
    const float* wr = top ? w1r : w2r;
    const float* wi = top ? w1i : w2i;
    float gr = 0.f, gi = 0.f;
    for (int i = 0; i < CI; ++i) {
      float2 f = *(const float2*)&F[(((size_t)b * CI + i) * KYp + kyp) * (HM * 2) + kx * 2];
      size_t wo = (((size_t)i * CO + o) * HM + m) * HM + kx;
      float wrv = wr[wo], wiv = wi[wo];
      gr = fmaf(f.x, wrv, gr); gr = fmaf(-f.y, wiv, gr);
      gi = fmaf(f.x, wiv, gi); gi = fmaf(f.y, wrv, gi);
    }
    Gs[(kyp * HM + kx) * 2]     = gr;
    Gs[(kyp * HM + kx) * 2 + 1] = gi;
  }
  __syncthreads();

  // ---- t1: thread = h row; same fmaf sequence as round 7 (bit-identical),
  //      but emits g row as bf16 hi/lo MFMA A-fragments ----
  {
    const int h = tid;
    float gr[16], gi[16];
    #pragma unroll
    for (int kx = 0; kx < 16; ++kx) { gr[kx] = 0.f; gi[kx] = 0.f; }
    #pragma unroll 4
    for (int kyp = 0; kyp < 32; ++kyp) {
      const int ky = (kyp < 16) ? kyp : (kyp + 480);
      const int t = (ky * h) & 511;
      const float cc = ct[t], ss = st[t];
      float4 row[8];
      #pragma unroll
      for (int j = 0; j < 8; ++j) row[j] = *(const float4*)&Gs[kyp * 32 + j * 4];
      #pragma unroll
      for (int kx = 0; kx < 16; ++kx) {
        float Gr = ((const float*)row)[2 * kx];
        float Gi = ((const float*)row)[2 * kx + 1];
        gr[kx] = fmaf(Gr, cc, gr[kx]); gr[kx] = fmaf(-Gi, ss, gr[kx]);
        gi[kx] = fmaf(Gr, ss, gi[kx]); gi[kx] = fmaf(Gi, cc, gi[kx]);
      }
    }
    // frag write: Afrag[mtile][s][lane = r + 32*half][j]: K = s*16+8*half+j
    const int mtile = h >> 5;
    const int r = h & 31;
    #pragma unroll
    for (int s = 0; s < 2; ++s) {
      #pragma unroll
      for (int half = 0; half < 2; ++half) {
        int k0 = s * 8 + half * 4;
        float4 va = make_float4(gr[k0], gi[k0], gr[k0 + 1], gi[k0 + 1]);
        float4 vb = make_float4(gr[k0 + 2], gi[k0 + 2], gr[k0 + 3], gi[k0 + 3]);
        uint2 ha, la, hb, lb;
        split4(va, ha, la);
        split4(vb, hb, lb);
        int off = ((mtile * 2 + s) * 64 + r + 32 * half) * 8;
        *(uint4*)&Ah[off] = make_uint4(ha.x, ha.y, hb.x, hb.y);
        *(uint4*)&Al[off] = make_uint4(la.x, la.y, lb.x, lb.y);
      }
    }
  }
  __syncthreads();

  // ---- t2: MFMA GEMM y = g[512x32] * T2[32x512], bias in C-init ----
  {
    float* yb = y + (size_t)blockIdx.x * (Hh * Ww);
    #pragma unroll
    for (int mm = 0; mm < 2; ++mm) {
      const int mtile = wid * 2 + mm;
      short8 a_h0 = *(const short8*)&Ah[((mtile * 2 + 0) * 64 + l) * 8];
      short8 a_h1 = *(const short8*)&Ah[((mtile * 2 + 1) * 64 + l) * 8];
      short8 a_l0 = *(const short8*)&Al[((mtile * 2 + 0) * 64 + l) * 8];
      short8 a_l1 = *(const short8*)&Al[((mtile * 2 + 1) * 64 + l) * 8];
      for (int n = 0; n < 16; ++n) {
        short8 b0 = *(const short8*)&T2l[((n * 2 + 0) * 64 + l) * 8];
        short8 b1 = *(const short8*)&T2l[((n * 2 + 1) * 64 + l) * 8];
        f32x16 acc;
        #pragma unroll
        for (int r = 0; r < 16; ++r) acc[r] = bv;
        acc = __builtin_amdgcn_mfma_f32_32x32x16_bf16(a_h0, b0, acc, 0, 0, 0);
        acc = __builtin_amdgcn_mfma_f32_32x32x16_bf16(a_l0, b0, acc, 0, 0, 0);
        acc = __builtin_amdgcn_mfma_f32_32x32x16_bf16(a_h1, b1, acc, 0, 0, 0);
        acc = __builtin_amdgcn_mfma_f32_32x32x16_bf16(a_l1, b1, acc, 0, 0, 0);
        const int col = n * 32 + (l & 31);
        const int rq = 4 * (l >> 5);
        #pragma unroll
        for (int r = 0; r < 16; ++r) {
          int row = mtile * 32 + (r & 3) + 8 * (r >> 2) + rq;
          yb[(size_t)row * Ww + col] = acc[r];
        }
      }
    }
  }
}

extern "C" void kernel_launch(void* const* d_in, const int* in_sizes, int n_in,
                              void* d_out, int out_size, void* d_ws, size_t ws_size,
                              hipStream_t stream) {
  const float* x    = (const float*)d_in[0];
  const float* w1r  = (const float*)d_in[1];
  const float* w1i  = (const float*)d_in[2];
  const float* w2r  = (const float*)d_in[3];
  const float* w2i  = (const float*)d_in[4];
  const float* bias = (const float*)d_in[5];
  float* y  = (float*)d_out;
  float* ws = (float*)d_ws;
  float* F   = ws + F_OFF;
  float* E   = ws + g_OFF;           // 32 KB
  float* E2c = ws + g_OFF + 8192;    // 64 KB
  float* T2f = ws + g_OFF + 24576;   // 32 KB

  hipLaunchKernelGGL(e_init_kernel, dim3(256), dim3(256), 0, stream, E);
  hipLaunchKernelGGL(fwd_kernel, dim3(Bb * CI), dim3(512), 0, stream, x, E, E2c, F);
  hipLaunchKernelGGL(bwd_kernel, dim3(Bb * CO), dim3(512), 0, stream, F,
                     w1r, w1i, w2r, w2i, bias, T2f, y);
}

// Round 9
// 146.887 us; speedup vs baseline: 1.6404x; 1.0343x over previous
//
#include <hip/hip_runtime.h>
#include <math.h>

#define Hh 512
#define Ww 512
#define Bb 8
#define CI 32
#define CO 32
#define HM 16   // kx modes kept
#define KYp 32  // packed ky modes (0..15 and 496..511)

static constexpr float TWO_PI = 6.28318530717958647692f;

// workspace layout (float offsets)
#define F_OFF  4194304u   // [B*CI][32][16][2] = 262,144 floats
#define g_OFF  4718592u   // E tables live here (only fwd/bwd read them)
// E   (bf16 phase-1 DFT frags, 32 KB)  at g_OFF
// E2c (bf16 phase-2 DFT frags, 64 KB)  at g_OFF + 8192
// T2f (bf16 t2 B-frags,        32 KB)  at g_OFF + 24576

using short8 = __attribute__((ext_vector_type(8))) short;
using f32x16 = __attribute__((ext_vector_type(16))) float;

__device__ inline unsigned short bf16_rn(float f) {
  unsigned u = __float_as_uint(f);
  u += 0x7FFFu + ((u >> 16) & 1u);
  return (unsigned short)(u >> 16);
}

// exact split of 4 floats into hi(bf16-trunc) + lo(residual as bf16)
__device__ inline void split4(float4 v, uint2& h2, uint2& l2) {
  unsigned u0 = __float_as_uint(v.x), u1 = __float_as_uint(v.y);
  unsigned u2 = __float_as_uint(v.z), u3 = __float_as_uint(v.w);
  float f0 = v.x - __uint_as_float(u0 & 0xFFFF0000u);
  float f1 = v.y - __uint_as_float(u1 & 0xFFFF0000u);
  float f2 = v.z - __uint_as_float(u2 & 0xFFFF0000u);
  float f3 = v.w - __uint_as_float(u3 & 0xFFFF0000u);
  h2.x = (u1 & 0xFFFF0000u) | (u0 >> 16);
  h2.y = (u3 & 0xFFFF0000u) | (u2 >> 16);
  l2.x = (__float_as_uint(f1) & 0xFFFF0000u) | (__float_as_uint(f0) >> 16);
  l2.y = (__float_as_uint(f3) & 0xFFFF0000u) | (__float_as_uint(f2) >> 16);
}

// --------- E init: all DFT-matrix fragment tables ------------------------
// idx 0..16383: E1; 16384..49151: E2c; 49152..65535: T2frag
__global__ __launch_bounds__(256) void e_init_kernel(float* __restrict__ Ef) {
  unsigned short* E = (unsigned short*)Ef;
  int idx = blockIdx.x * 256 + threadIdx.x;   // 0..65535
  if (idx < 16384) {
    int kk = idx >> 9;
    int l = (idx >> 3) & 63;
    int j = idx & 7;
    int k = kk * 16 + 8 * (l >> 5) + j;
    int col = l & 31;
    int kx = col >> 1;
    int t = (kx * k) & 511;
    float sv, cv;
    sincosf(TWO_PI * (float)t / 512.0f, &sv, &cv);
    E[idx] = bf16_rn((col & 1) ? -sv : cv);
  } else if (idx < 49152) {
    int idx2 = idx - 16384;
    int mt = idx2 >> 14;
    int rem = idx2 & 16383;
    int kk = rem >> 9;
    int l = (rem >> 3) & 63;
    int j = rem & 7;
    int h = kk * 16 + 8 * (l >> 5) + j;
    int kyc = l & 31;
    int kyp = mt * 16 + (kyc >> 1);
    int ky = (kyp < 16) ? kyp : (kyp + 480);
    int t = (ky * h) & 511;
    float sv, cv;
    sincosf(TWO_PI * (float)t / 512.0f, &sv, &cv);
    E[idx] = bf16_rn((kyc & 1) ? -sv : cv);
  } else {
    // T2frag[ntile 16][s 2][lane 64][j 8]:
    //   K = s*16 + 8*(l>>5) + j = 2k+c ; w = ntile*32 + (l&31)
    //   val = inv * wk * (c ? -sin : cos)(2pi k w/512), wk = (k==0?1:2)
    int rem = idx - 49152;                 // 0..16383
    int ntile = rem >> 10;
    int s = (rem >> 9) & 1;
    int l = (rem >> 3) & 63;
    int j = rem & 7;
    int K = s * 16 + 8 * (l >> 5) + j;
    int k = K >> 1, c = K & 1;
    int w = ntile * 32 + (l & 31);
    int t = (k * w) & 511;
    float sv, cv;
    sincosf(TWO_PI * (float)t / 512.0f, &sv, &cv);
    float wk = (k == 0) ? 1.0f : 2.0f;
    float inv = 1.0f / 262144.0f;
    E[idx] = bf16_rn(inv * wk * (c ? -sv : cv));
  }
}

// ---------------- fwd: x image -> F (unchanged from round 5) -------------
__global__ __launch_bounds__(512) void fwd_kernel(const float* __restrict__ x,
                                                  const float* __restrict__ Ef,
                                                  const float* __restrict__ E2f,
                                                  float* __restrict__ F) {
  __shared__ char lds[135168];
  short* E2l = (short*)lds;                 // [mt 2][kk 32][64][8]  64 KB
  short* Xh  = (short*)(lds + 65536);       // [kc 32][64][8]        32 KB
  short* Xl  = (short*)(lds + 98304);       //                       32 KB
  float* red = (float*)(lds + 65536);       // alias Xh
  short* Ah  = (short*)(lds + 131072);      // [kc2 2][64][8]         2 KB
  short* Al  = (short*)(lds + 133120);      //                        2 KB
  float* Pbuf = (float*)(lds + 65536);      // final reduce (alias)

  const int tid = threadIdx.x;
  const int l = tid & 63;
  const int wid = tid >> 6;
  const int bi = blockIdx.x;
  const float* xb = x + (size_t)bi * (Hh * Ww);

  {
    const float4* Eg = (const float4*)E2f;
    float4* El4 = (float4*)E2l;
    #pragma unroll
    for (int j = 0; j < 8; ++j) El4[tid + j * 512] = Eg[tid + j * 512];
  }
  short8 e1[4];
  {
    const short* Eg = (const short*)Ef;
    #pragma unroll
    for (int c = 0; c < 4; ++c)
      e1[c] = *(const short8*)(Eg + ((size_t)(4 * wid + c) * 64 + l) * 8);
  }

  const int hb = (l >> 1) & 1;
  const int jfr = 4 * (l & 1);
  const int kc0 = l >> 2;

  float4 rv[8];
  #pragma unroll
  for (int j = 0; j < 4; ++j) {
    const float* rowp = xb + (size_t)(wid * 4 + j) * 512;
    rv[2 * j]     = *(const float4*)(rowp + 4 * l);
    rv[2 * j + 1] = *(const float4*)(rowp + 256 + 4 * l);
  }

  f32x16 acc1 = {0.f,0.f,0.f,0.f,0.f,0.f,0.f,0.f,0.f,0.f,0.f,0.f,0.f,0.f,0.f,0.f};
  f32x16 acc2 = {0.f,0.f,0.f,0.f,0.f,0.f,0.f,0.f,0.f,0.f,0.f,0.f,0.f,0.f,0.f,0.f};

  const int mt2 = wid & 1, kc2w = (wid >> 1) & 1, part2 = wid >> 2;

  for (int s = 0; s < 16; ++s) {
    if (s > 0) {
      short8 a2 = *(const short8*)&E2l[((mt2 * 32 + ((s - 1) * 2 + kc2w)) * 64 + l) * 8];
      short8 b2 = part2 ? *(const short8*)&Al[(kc2w * 64 + l) * 8]
                        : *(const short8*)&Ah[(kc2w * 64 + l) * 8];
      acc2 = __builtin_amdgcn_mfma_f32_32x32x16_bf16(a2, b2, acc2, 0, 0, 0);
    }
    #pragma unroll
    for (int j = 0; j < 4; ++j) {
      #pragma unroll
      for (int hf = 0; hf < 2; ++hf) {
        int kc = hf * 16 + kc0;
        int lanep = (wid * 4 + j) + 32 * hb;
        int off = ((kc * 64) + (lanep ^ (kc & 7))) * 8 + jfr;
        uint2 h2, l2;
        split4(rv[2 * j + hf], h2, l2);
        *(uint2*)&Xh[off] = h2;
        *(uint2*)&Xl[off] = l2;
      }
    }
    if (s < 15) {
      #pragma unroll
      for (int j = 0; j < 4; ++j) {
        const float* rowp = xb + (size_t)((s + 1) * 32 + wid * 4 + j) * 512;
        rv[2 * j]     = *(const float4*)(rowp + 4 * l);
        rv[2 * j + 1] = *(const float4*)(rowp + 256 + 4 * l);
      }
    }
    __syncthreads();
    #pragma unroll
    for (int c = 0; c < 4; ++c) {
      int kc = 4 * wid + c;
      int slot = ((kc * 64) + (l ^ (kc & 7))) * 8;
      short8 hi = *(const short8*)&Xh[slot];
      short8 lo = *(const short8*)&Xl[slot];
      acc1 = __builtin_amdgcn_mfma_f32_32x32x16_bf16(hi, e1[c], acc1, 0, 0, 0);
      acc1 = __builtin_amdgcn_mfma_f32_32x32x16_bf16(lo, e1[c], acc1, 0, 0, 0);
    }
    __syncthreads();
    #pragma unroll
    for (int q = 0; q < 4; ++q)
      *(float4*)&red[((wid * 4 + q) * 64 + l) * 4] =
          make_float4(acc1[4*q], acc1[4*q+1], acc1[4*q+2], acc1[4*q+3]);
    #pragma unroll
    for (int r = 0; r < 16; ++r) acc1[r] = 0.f;
    __syncthreads();
    if (wid < 4) {
      const int q = wid;
      float4 sum = make_float4(0.f, 0.f, 0.f, 0.f);
      #pragma unroll
      for (int w = 0; w < 8; ++w) {
        float4 v = *(const float4*)&red[((w * 4 + q) * 64 + l) * 4];
        sum.x += v.x; sum.y += v.y; sum.z += v.z; sum.w += v.w;
      }
      uint2 h2, l2;
      split4(sum, h2, l2);
      int off = ((q >> 1) * 64 + ((l & 31) + 32 * (q & 1))) * 8 + 4 * (l >> 5);
      *(uint2*)&Ah[off] = h2;
      *(uint2*)&Al[off] = l2;
    }
    __syncthreads();
  }
  {
    short8 a2 = *(const short8*)&E2l[((mt2 * 32 + (15 * 2 + kc2w)) * 64 + l) * 8];
    short8 b2 = part2 ? *(const short8*)&Al[(kc2w * 64 + l) * 8]
                      : *(const short8*)&Ah[(kc2w * 64 + l) * 8];
    acc2 = __builtin_amdgcn_mfma_f32_32x32x16_bf16(a2, b2, acc2, 0, 0, 0);
  }
  #pragma unroll
  for (int r4 = 0; r4 < 4; ++r4)
    *(float4*)&Pbuf[((wid * 4 + r4) * 64 + l) * 4] =
        make_float4(acc2[4*r4], acc2[4*r4+1], acc2[4*r4+2], acc2[4*r4+3]);
  __syncthreads();

  if (wid < 2) {
    const int mt = wid;
    float S[16];
    #pragma unroll
    for (int r = 0; r < 16; ++r) S[r] = 0.f;
    #pragma unroll
    for (int p = 0; p < 4; ++p) {
      #pragma unroll
      for (int r4 = 0; r4 < 4; ++r4) {
        float4 v = *(const float4*)&Pbuf[(((mt + 2 * p) * 4 + r4) * 64 + l) * 4];
        S[4*r4]   += v.x; S[4*r4+1] += v.y; S[4*r4+2] += v.z; S[4*r4+3] += v.w;
      }
    }
    const int c = l & 1;
    #pragma unroll
    for (int q = 0; q < 8; ++q) {
      int r0 = 2 * q;
      float T = __shfl_xor(S[r0 + 1], 1, 64);
      float val = c ? (S[r0] + T) : (S[r0] - T);
      int kyp_loc = ((r0 & 3) >> 1) + 4 * (r0 >> 2) + 2 * (l >> 5);
      F[((size_t)bi * 32 + mt * 16 + kyp_loc) * 32 + (l & 31)] = val;
    }
  }
}

// ---------------- bwd: F -> y (mix + t1 scalar, t2 MFMA + LDS-coalesced
//                  stores). One block per (b,o), 512 threads. LDS 136 KB.
__global__ __launch_bounds__(512) void bwd_kernel(const float* __restrict__ F,
    const float* __restrict__ w1r, const float* __restrict__ w1i,
    const float* __restrict__ w2r, const float* __restrict__ w2i,
    const float* __restrict__ bias, const float* __restrict__ T2f,
    float* __restrict__ y) {
  __shared__ char lds[139264];
  short* Ah   = (short*)lds;                // [mtile 16][s 2][64][8] 32 KB
  short* Al   = (short*)(lds + 32768);      // 32 KB
  float* ybuf = (float*)(lds + 65536);      // [32][512]              64 KB
  float* Gs   = (float*)(lds + 131072);     // [kyp 32][kx 16][2]      4 KB
  float* ct   = (float*)(lds + 135168);     // 2 KB
  float* st   = (float*)(lds + 137216);     // 2 KB

  const int tid = threadIdx.x;
  const int l = tid & 63;
  const int wid = tid >> 6;
  const int b = blockIdx.x >> 5;
  const int o = blockIdx.x & 31;
  const float bv = bias[o];

  // B-fragments for this wave's 2 ntiles -> 16 VGPRs (reused all chunks)
  short8 bfr[4];
  {
    const short* Tg = (const short*)T2f;
    #pragma unroll
    for (int q = 0; q < 4; ++q) {
      int nt = wid * 2 + (q >> 1);
      int s = q & 1;
      bfr[q] = *(const short8*)(Tg + ((size_t)(nt * 2 + s) * 64 + l) * 8);
    }
  }
  // twiddle table (1 sincosf/thread)
  {
    float sv, cv;
    sincosf(TWO_PI * (float)tid / 512.0f, &sv, &cv);
    ct[tid] = cv;
    st[tid] = sv;
  }

  // ---- mix: one complex G mode per thread ----
  {
    const int kyp = tid >> 4;
    const int kx = tid & 15;
    const bool top = kyp < 16;
    const int m = top ? kyp : (kyp - 16);
    const float* wr = top ? w1r : w2r;
    const float* wi = top ? w1i : w2i;
    float gr = 0.f, gi = 0.f;
    for (int i = 0; i < CI; ++i) {
      float2 f = *(const float2*)&F[(((size_t)b * CI + i) * KYp + kyp) * (HM * 2) + kx * 2];
      size_t wo = (((size_t)i * CO + o) * HM + m) * HM + kx;
      float wrv = wr[wo], wiv = wi[wo];
      gr = fmaf(f.x, wrv, gr); gr = fmaf(-f.y, wiv, gr);
      gi = fmaf(f.x, wiv, gi); gi = fmaf(f.y, wrv, gi);
    }
    Gs[(kyp * HM + kx) * 2]     = gr;
    Gs[(kyp * HM + kx) * 2 + 1] = gi;
  }
  __syncthreads();

  // ---- t1: thread = h row; emits g row as bf16 hi/lo MFMA A-fragments ----
  {
    const int h = tid;
    float gr[16], gi[16];
    #pragma unroll
    for (int kx = 0; kx < 16; ++kx) { gr[kx] = 0.f; gi[kx] = 0.f; }
    #pragma unroll 4
    for (int kyp = 0; kyp < 32; ++kyp) {
      const int ky = (kyp < 16) ? kyp : (kyp + 480);
      const int t = (ky * h) & 511;
      const float cc = ct[t], ss = st[t];
      float4 row[8];
      #pragma unroll
      for (int j = 0; j < 8; ++j) row[j] = *(const float4*)&Gs[kyp * 32 + j * 4];
      #pragma unroll
      for (int kx = 0; kx < 16; ++kx) {
        float Gr = ((const float*)row)[2 * kx];
        float Gi = ((const float*)row)[2 * kx + 1];
        gr[kx] = fmaf(Gr, cc, gr[kx]); gr[kx] = fmaf(-Gi, ss, gr[kx]);
        gi[kx] = fmaf(Gr, ss, gi[kx]); gi[kx] = fmaf(Gi, cc, gi[kx]);
      }
    }
    const int mtile = h >> 5;
    const int r = h & 31;
    #pragma unroll
    for (int s = 0; s < 2; ++s) {
      #pragma unroll
      for (int half = 0; half < 2; ++half) {
        int k0 = s * 8 + half * 4;
        float4 va = make_float4(gr[k0], gi[k0], gr[k0 + 1], gi[k0 + 1]);
        float4 vb = make_float4(gr[k0 + 2], gi[k0 + 2], gr[k0 + 3], gi[k0 + 3]);
        uint2 ha, la, hb, lb;
        split4(va, ha, la);
        split4(vb, hb, lb);
        int off = ((mtile * 2 + s) * 64 + r + 32 * half) * 8;
        *(uint4*)&Ah[off] = make_uint4(ha.x, ha.y, hb.x, hb.y);
        *(uint4*)&Al[off] = make_uint4(la.x, la.y, lb.x, lb.y);
      }
    }
  }
  __syncthreads();

  // ---- t2: per mtile chunk: MFMA -> ybuf -> coalesced 1KB/inst stores ----
  {
    float* yb = y + (size_t)blockIdx.x * (Hh * Ww);
    for (int mtile = 0; mtile < 16; ++mtile) {
      short8 a_h0 = *(const short8*)&Ah[((mtile * 2 + 0) * 64 + l) * 8];
      short8 a_l0 = *(const short8*)&Al[((mtile * 2 + 0) * 64 + l) * 8];
      short8 a_h1 = *(const short8*)&Ah[((mtile * 2 + 1) * 64 + l) * 8];
      short8 a_l1 = *(const short8*)&Al[((mtile * 2 + 1) * 64 + l) * 8];
      #pragma unroll
      for (int t = 0; t < 2; ++t) {
        const int ntile = wid * 2 + t;
        f32x16 acc;
        #pragma unroll
        for (int r = 0; r < 16; ++r) acc[r] = bv;
        acc = __builtin_amdgcn_mfma_f32_32x32x16_bf16(a_h0, bfr[2*t+0], acc, 0, 0, 0);
        acc = __builtin_amdgcn_mfma_f32_32x32x16_bf16(a_l0, bfr[2*t+0], acc, 0, 0, 0);
        acc = __builtin_amdgcn_mfma_f32_32x32x16_bf16(a_h1, bfr[2*t+1], acc, 0, 0, 0);
        acc = __builtin_amdgcn_mfma_f32_32x32x16_bf16(a_l1, bfr[2*t+1], acc, 0, 0, 0);
        const int col = ntile * 32 + (l & 31);
        const int rq = 4 * (l >> 5);
        #pragma unroll
        for (int r = 0; r < 16; ++r)
          ybuf[((r & 3) + 8 * (r >> 2) + rq) * 512 + col] = acc[r];
      }
      __syncthreads();
      {
        const float4* yb4 = (const float4*)ybuf;
        #pragma unroll
        for (int j = 0; j < 8; ++j) {
          int f4 = tid + j * 512;
          *(float4*)(yb + (size_t)(mtile * 32 + (f4 >> 7)) * 512 + (f4 & 127) * 4) = yb4[f4];
        }
      }
      __syncthreads();
    }
  }
}

extern "C" void kernel_launch(void* const* d_in, const int* in_sizes, int n_in,
                              void* d_out, int out_size, void* d_ws, size_t ws_size,
                              hipStream_t stream) {
  const float* x    = (const float*)d_in[0];
  const float* w1r  = (const float*)d_in[1];
  const float* w1i  = (const float*)d_in[2];
  const float* w2r  = (const float*)d_in[3];
  const float* w2i  = (const float*)d_in[4];
  const float* bias = (const float*)d_in[5];
  float* y  = (float*)d_out;
  float* ws = (float*)d_ws;
  float* F   = ws + F_OFF;
  float* E   = ws + g_OFF;           // 32 KB
  float* E2c = ws + g_OFF + 8192;    // 64 KB
  float* T2f = ws + g_OFF + 24576;   // 32 KB

  hipLaunchKernelGGL(e_init_kernel, dim3(256), dim3(256), 0, stream, E);
  hipLaunchKernelGGL(fwd_kernel, dim3(Bb * CI), dim3(512), 0, stream, x, E, E2c, F);
  hipLaunchKernelGGL(bwd_kernel, dim3(Bb * CO), dim3(512), 0, stream, F,
                     w1r, w1i, w2r, w2i, bias, T2f, y);
}

// Round 10
// 142.903 us; speedup vs baseline: 1.6861x; 1.0279x over previous
//
#include <hip/hip_runtime.h>
#include <math.h>

#define Hh 512
#define Ww 512
#define Bb 8
#define CI 32
#define CO 32
#define HM 16   // kx modes kept
#define KYp 32  // packed ky modes (0..15 and 496..511)

static constexpr float TWO_PI = 6.28318530717958647692f;

// workspace layout (float offsets)
#define F_OFF  4194304u   // [B*CI][32][16][2] = 262,144 floats
#define g_OFF  4718592u   // E tables live here (only fwd/bwd read them)
// E   (bf16 phase-1 DFT frags, 32 KB)  at g_OFF
// E2c (bf16 phase-2 DFT frags, 64 KB)  at g_OFF + 8192
// T2f (bf16 t2 B-frags,        32 KB)  at g_OFF + 24576

using short8 = __attribute__((ext_vector_type(8))) short;
using f32x16 = __attribute__((ext_vector_type(16))) float;

__device__ inline unsigned short bf16_rn(float f) {
  unsigned u = __float_as_uint(f);
  u += 0x7FFFu + ((u >> 16) & 1u);
  return (unsigned short)(u >> 16);
}

// exact split of 4 floats into hi(bf16-trunc) + lo(residual as bf16)
__device__ inline void split4(float4 v, uint2& h2, uint2& l2) {
  unsigned u0 = __float_as_uint(v.x), u1 = __float_as_uint(v.y);
  unsigned u2 = __float_as_uint(v.z), u3 = __float_as_uint(v.w);
  float f0 = v.x - __uint_as_float(u0 & 0xFFFF0000u);
  float f1 = v.y - __uint_as_float(u1 & 0xFFFF0000u);
  float f2 = v.z - __uint_as_float(u2 & 0xFFFF0000u);
  float f3 = v.w - __uint_as_float(u3 & 0xFFFF0000u);
  h2.x = (u1 & 0xFFFF0000u) | (u0 >> 16);
  h2.y = (u3 & 0xFFFF0000u) | (u2 >> 16);
  l2.x = (__float_as_uint(f1) & 0xFFFF0000u) | (__float_as_uint(f0) >> 16);
  l2.y = (__float_as_uint(f3) & 0xFFFF0000u) | (__float_as_uint(f2) >> 16);
}

// --------- E init: all DFT-matrix fragment tables ------------------------
// idx 0..16383: E1; 16384..49151: E2c; 49152..65535: T2frag
__global__ __launch_bounds__(256) void e_init_kernel(float* __restrict__ Ef) {
  unsigned short* E = (unsigned short*)Ef;
  int idx = blockIdx.x * 256 + threadIdx.x;   // 0..65535
  if (idx < 16384) {
    int kk = idx >> 9;
    int l = (idx >> 3) & 63;
    int j = idx & 7;
    int k = kk * 16 + 8 * (l >> 5) + j;
    int col = l & 31;
    int kx = col >> 1;
    int t = (kx * k) & 511;
    float sv, cv;
    sincosf(TWO_PI * (float)t / 512.0f, &sv, &cv);
    E[idx] = bf16_rn((col & 1) ? -sv : cv);
  } else if (idx < 49152) {
    int idx2 = idx - 16384;
    int mt = idx2 >> 14;
    int rem = idx2 & 16383;
    int kk = rem >> 9;
    int l = (rem >> 3) & 63;
    int j = rem & 7;
    int h = kk * 16 + 8 * (l >> 5) + j;
    int kyc = l & 31;
    int kyp = mt * 16 + (kyc >> 1);
    int ky = (kyp < 16) ? kyp : (kyp + 480);
    int t = (ky * h) & 511;
    float sv, cv;
    sincosf(TWO_PI * (float)t / 512.0f, &sv, &cv);
    E[idx] = bf16_rn((kyc & 1) ? -sv : cv);
  } else {
    // T2frag[ntile 16][s 2][lane 64][j 8]:
    //   K = s*16 + 8*(l>>5) + j = 2k+c ; w = ntile*32 + (l&31)
    //   val = inv * wk * (c ? -sin : cos)(2pi k w/512), wk = (k==0?1:2)
    int rem = idx - 49152;                 // 0..16383
    int ntile = rem >> 10;
    int s = (rem >> 9) & 1;
    int l = (rem >> 3) & 63;
    int j = rem & 7;
    int K = s * 16 + 8 * (l >> 5) + j;
    int k = K >> 1, c = K & 1;
    int w = ntile * 32 + (l & 31);
    int t = (k * w) & 511;
    float sv, cv;
    sincosf(TWO_PI * (float)t / 512.0f, &sv, &cv);
    float wk = (k == 0) ? 1.0f : 2.0f;
    float inv = 1.0f / 262144.0f;
    E[idx] = bf16_rn(inv * wk * (c ? -sv : cv));
  }
}

// ---------------- fwd: x image -> F (unchanged from round 5) -------------
__global__ __launch_bounds__(512) void fwd_kernel(const float* __restrict__ x,
                                                  const float* __restrict__ Ef,
                                                  const float* __restrict__ E2f,
                                                  float* __restrict__ F) {
  __shared__ char lds[135168];
  short* E2l = (short*)lds;                 // [mt 2][kk 32][64][8]  64 KB
  short* Xh  = (short*)(lds + 65536);       // [kc 32][64][8]        32 KB
  short* Xl  = (short*)(lds + 98304);       //                       32 KB
  float* red = (float*)(lds + 65536);       // alias Xh
  short* Ah  = (short*)(lds + 131072);      // [kc2 2][64][8]         2 KB
  short* Al  = (short*)(lds + 133120);      //                        2 KB
  float* Pbuf = (float*)(lds + 65536);      // final reduce (alias)

  const int tid = threadIdx.x;
  const int l = tid & 63;
  const int wid = tid >> 6;
  const int bi = blockIdx.x;
  const float* xb = x + (size_t)bi * (Hh * Ww);

  {
    const float4* Eg = (const float4*)E2f;
    float4* El4 = (float4*)E2l;
    #pragma unroll
    for (int j = 0; j < 8; ++j) El4[tid + j * 512] = Eg[tid + j * 512];
  }
  short8 e1[4];
  {
    const short* Eg = (const short*)Ef;
    #pragma unroll
    for (int c = 0; c < 4; ++c)
      e1[c] = *(const short8*)(Eg + ((size_t)(4 * wid + c) * 64 + l) * 8);
  }

  const int hb = (l >> 1) & 1;
  const int jfr = 4 * (l & 1);
  const int kc0 = l >> 2;

  float4 rv[8];
  #pragma unroll
  for (int j = 0; j < 4; ++j) {
    const float* rowp = xb + (size_t)(wid * 4 + j) * 512;
    rv[2 * j]     = *(const float4*)(rowp + 4 * l);
    rv[2 * j + 1] = *(const float4*)(rowp + 256 + 4 * l);
  }

  f32x16 acc1 = {0.f,0.f,0.f,0.f,0.f,0.f,0.f,0.f,0.f,0.f,0.f,0.f,0.f,0.f,0.f,0.f};
  f32x16 acc2 = {0.f,0.f,0.f,0.f,0.f,0.f,0.f,0.f,0.f,0.f,0.f,0.f,0.f,0.f,0.f,0.f};

  const int mt2 = wid & 1, kc2w = (wid >> 1) & 1, part2 = wid >> 2;

  for (int s = 0; s < 16; ++s) {
    if (s > 0) {
      short8 a2 = *(const short8*)&E2l[((mt2 * 32 + ((s - 1) * 2 + kc2w)) * 64 + l) * 8];
      short8 b2 = part2 ? *(const short8*)&Al[(kc2w * 64 + l) * 8]
                        : *(const short8*)&Ah[(kc2w * 64 + l) * 8];
      acc2 = __builtin_amdgcn_mfma_f32_32x32x16_bf16(a2, b2, acc2, 0, 0, 0);
    }
    #pragma unroll
    for (int j = 0; j < 4; ++j) {
      #pragma unroll
      for (int hf = 0; hf < 2; ++hf) {
        int kc = hf * 16 + kc0;
        int lanep = (wid * 4 + j) + 32 * hb;
        int off = ((kc * 64) + (lanep ^ (kc & 7))) * 8 + jfr;
        uint2 h2, l2;
        split4(rv[2 * j + hf], h2, l2);
        *(uint2*)&Xh[off] = h2;
        *(uint2*)&Xl[off] = l2;
      }
    }
    if (s < 15) {
      #pragma unroll
      for (int j = 0; j < 4; ++j) {
        const float* rowp = xb + (size_t)((s + 1) * 32 + wid * 4 + j) * 512;
        rv[2 * j]     = *(const float4*)(rowp + 4 * l);
        rv[2 * j + 1] = *(const float4*)(rowp + 256 + 4 * l);
      }
    }
    __syncthreads();
    #pragma unroll
    for (int c = 0; c < 4; ++c) {
      int kc = 4 * wid + c;
      int slot = ((kc * 64) + (l ^ (kc & 7))) * 8;
      short8 hi = *(const short8*)&Xh[slot];
      short8 lo = *(const short8*)&Xl[slot];
      acc1 = __builtin_amdgcn_mfma_f32_32x32x16_bf16(hi, e1[c], acc1, 0, 0, 0);
      acc1 = __builtin_amdgcn_mfma_f32_32x32x16_bf16(lo, e1[c], acc1, 0, 0, 0);
    }
    __syncthreads();
    #pragma unroll
    for (int q = 0; q < 4; ++q)
      *(float4*)&red[((wid * 4 + q) * 64 + l) * 4] =
          make_float4(acc1[4*q], acc1[4*q+1], acc1[4*q+2], acc1[4*q+3]);
    #pragma unroll
    for (int r = 0; r < 16; ++r) acc1[r] = 0.f;
    __syncthreads();
    if (wid < 4) {
      const int q = wid;
      float4 sum = make_float4(0.f, 0.f, 0.f, 0.f);
      #pragma unroll
      for (int w = 0; w < 8; ++w) {
        float4 v = *(const float4*)&red[((w * 4 + q) * 64 + l) * 4];
        sum.x += v.x; sum.y += v.y; sum.z += v.z; sum.w += v.w;
      }
      uint2 h2, l2;
      split4(sum, h2, l2);
      int off = ((q >> 1) * 64 + ((l & 31) + 32 * (q & 1))) * 8 + 4 * (l >> 5);
      *(uint2*)&Ah[off] = h2;
      *(uint2*)&Al[off] = l2;
    }
    __syncthreads();
  }
  {
    short8 a2 = *(const short8*)&E2l[((mt2 * 32 + (15 * 2 + kc2w)) * 64 + l) * 8];
    short8 b2 = part2 ? *(const short8*)&Al[(kc2w * 64 + l) * 8]
                      : *(const short8*)&Ah[(kc2w * 64 + l) * 8];
    acc2 = __builtin_amdgcn_mfma_f32_32x32x16_bf16(a2, b2, acc2, 0, 0, 0);
  }
  #pragma unroll
  for (int r4 = 0; r4 < 4; ++r4)
    *(float4*)&Pbuf[((wid * 4 + r4) * 64 + l) * 4] =
        make_float4(acc2[4*r4], acc2[4*r4+1], acc2[4*r4+2], acc2[4*r4+3]);
  __syncthreads();

  if (wid < 2) {
    const int mt = wid;
    float S[16];
    #pragma unroll
    for (int r = 0; r < 16; ++r) S[r] = 0.f;
    #pragma unroll
    for (int p = 0; p < 4; ++p) {
      #pragma unroll
      for (int r4 = 0; r4 < 4; ++r4) {
        float4 v = *(const float4*)&Pbuf[(((mt + 2 * p) * 4 + r4) * 64 + l) * 4];
        S[4*r4]   += v.x; S[4*r4+1] += v.y; S[4*r4+2] += v.z; S[4*r4+3] += v.w;
      }
    }
    const int c = l & 1;
    #pragma unroll
    for (int q = 0; q < 8; ++q) {
      int r0 = 2 * q;
      float T = __shfl_xor(S[r0 + 1], 1, 64);
      float val = c ? (S[r0] + T) : (S[r0] - T);
      int kyp_loc = ((r0 & 3) >> 1) + 4 * (r0 >> 2) + 2 * (l >> 5);
      F[((size_t)bi * 32 + mt * 16 + kyp_loc) * 32 + (l & 31)] = val;
    }
  }
}

// ---------------- bwd: F -> y. One block per (b,o,row-half): 512 blocks,
//  512 thr, 40 KB LDS -> 2 blocks/CU so stores overlap compute via TLP.
__global__ __launch_bounds__(512, 4) void bwd_kernel(const float* __restrict__ F,
    const float* __restrict__ w1r, const float* __restrict__ w1i,
    const float* __restrict__ w2r, const float* __restrict__ w2i,
    const float* __restrict__ bias, const float* __restrict__ T2f,
    float* __restrict__ y) {
  __shared__ char lds[40960];
  short* Ah = (short*)lds;                  // [mt_loc 8][s 2][64][8] 16 KB
  short* Al = (short*)(lds + 16384);        // 16 KB
  float* Gs = (float*)(lds + 32768);        // [kyp 32][kx 16][2]      4 KB
  float* ct = (float*)(lds + 36864);        // 2 KB
  float* st = (float*)(lds + 38912);        // 2 KB

  const int tid = threadIdx.x;
  const int l = tid & 63;
  const int wid = tid >> 6;
  const int bo = blockIdx.x >> 1;      // b*CO + o
  const int half = blockIdx.x & 1;     // row half (h in [half*256, +256))
  const int b = bo >> 5;
  const int o = bo & 31;
  const float bv = bias[o];

  // B-fragments for this wave's 2 ntiles -> 16 VGPRs
  short8 bfr[4];
  {
    const short* Tg = (const short*)T2f;
    #pragma unroll
    for (int q = 0; q < 4; ++q) {
      int nt = wid * 2 + (q >> 1);
      int s = q & 1;
      bfr[q] = *(const short8*)(Tg + ((size_t)(nt * 2 + s) * 64 + l) * 8);
    }
  }
  // twiddle table
  {
    float sv, cv;
    sincosf(TWO_PI * (float)tid / 512.0f, &sv, &cv);
    ct[tid] = cv;
    st[tid] = sv;
  }

  // ---- mix: one complex G mode per thread (duplicated across halves) ----
  {
    const int kyp = tid >> 4;
    const int kx = tid & 15;
    const bool top = kyp < 16;
    const int m = top ? kyp : (kyp - 16);
    const float* wr = top ? w1r : w2r;
    const float* wi = top ? w1i : w2i;
    float gr = 0.f, gi = 0.f;
    for (int i = 0; i < CI; ++i) {
      float2 f = *(const float2*)&F[(((size_t)b * CI + i) * KYp + kyp) * (HM * 2) + kx * 2];
      size_t wo = (((size_t)i * CO + o) * HM + m) * HM + kx;
      float wrv = wr[wo], wiv = wi[wo];
      gr = fmaf(f.x, wrv, gr); gr = fmaf(-f.y, wiv, gr);
      gi = fmaf(f.x, wiv, gi); gi = fmaf(f.y, wrv, gi);
    }
    Gs[(kyp * HM + kx) * 2]     = gr;
    Gs[(kyp * HM + kx) * 2 + 1] = gi;
  }
  __syncthreads();

  // ---- t1: thread = (row r in half, kx-half); 8 kx each; same fmaf chain
  //      per element as round 9 -> bit-identical sums ----
  {
    const int r = tid & 255;           // row within half
    const int h = half * 256 + r;
    const int kxh = tid >> 8;          // kx 8*kxh .. 8*kxh+7
    float gr[8], gi[8];
    #pragma unroll
    for (int k = 0; k < 8; ++k) { gr[k] = 0.f; gi[k] = 0.f; }
    #pragma unroll 4
    for (int kyp = 0; kyp < 32; ++kyp) {
      const int ky = (kyp < 16) ? kyp : (kyp + 480);
      const int t = (ky * h) & 511;
      const float cc = ct[t], ss = st[t];
      float4 row[4];
      #pragma unroll
      for (int j = 0; j < 4; ++j) row[j] = *(const float4*)&Gs[kyp * 32 + kxh * 16 + j * 4];
      #pragma unroll
      for (int k = 0; k < 8; ++k) {
        float Gr = ((const float*)row)[2 * k];
        float Gi = ((const float*)row)[2 * k + 1];
        gr[k] = fmaf(Gr, cc, gr[k]); gr[k] = fmaf(-Gi, ss, gr[k]);
        gi[k] = fmaf(Gr, ss, gi[k]); gi[k] = fmaf(Gi, cc, gi[k]);
      }
    }
    // frag write: s = kxh; K = s*16 + 8*hf2 + j
    const int mt_loc = r >> 5;
    const int rr = r & 31;
    const int s = kxh;
    #pragma unroll
    for (int hf2 = 0; hf2 < 2; ++hf2) {
      int k0 = hf2 * 4;   // local kx
      float4 va = make_float4(gr[k0], gi[k0], gr[k0 + 1], gi[k0 + 1]);
      float4 vb = make_float4(gr[k0 + 2], gi[k0 + 2], gr[k0 + 3], gi[k0 + 3]);
      uint2 ha, la, hb, lb;
      split4(va, ha, la);
      split4(vb, hb, lb);
      int off = ((mt_loc * 2 + s) * 64 + rr + 32 * hf2) * 8;
      *(uint4*)&Ah[off] = make_uint4(ha.x, ha.y, hb.x, hb.y);
      *(uint4*)&Al[off] = make_uint4(la.x, la.y, lb.x, lb.y);
    }
  }
  __syncthreads();

  // ---- t2: MFMA + direct stores, NO barriers (stores pipeline freely) ----
  {
    float* yb = y + (size_t)bo * (Hh * Ww) + (size_t)half * 256 * Ww;
    for (int mt = 0; mt < 8; ++mt) {
      short8 a_h0 = *(const short8*)&Ah[((mt * 2 + 0) * 64 + l) * 8];
      short8 a_l0 = *(const short8*)&Al[((mt * 2 + 0) * 64 + l) * 8];
      short8 a_h1 = *(const short8*)&Ah[((mt * 2 + 1) * 64 + l) * 8];
      short8 a_l1 = *(const short8*)&Al[((mt * 2 + 1) * 64 + l) * 8];
      #pragma unroll
      for (int t = 0; t < 2; ++t) {
        const int ntile = wid * 2 + t;
        f32x16 acc;
        #pragma unroll
        for (int r = 0; r < 16; ++r) acc[r] = bv;
        acc = __builtin_amdgcn_mfma_f32_32x32x16_bf16(a_h0, bfr[2*t+0], acc, 0, 0, 0);
        acc = __builtin_amdgcn_mfma_f32_32x32x16_bf16(a_l0, bfr[2*t+0], acc, 0, 0, 0);
        acc = __builtin_amdgcn_mfma_f32_32x32x16_bf16(a_h1, bfr[2*t+1], acc, 0, 0, 0);
        acc = __builtin_amdgcn_mfma_f32_32x32x16_bf16(a_l1, bfr[2*t+1], acc, 0, 0, 0);
        const int col = ntile * 32 + (l & 31);
        const int rq = 4 * (l >> 5);
        #pragma unroll
        for (int r = 0; r < 16; ++r) {
          int row = mt * 32 + (r & 3) + 8 * (r >> 2) + rq;
          yb[(size_t)row * Ww + col] = acc[r];
        }
      }
    }
  }
}

extern "C" void kernel_launch(void* const* d_in, const int* in_sizes, int n_in,
                              void* d_out, int out_size, void* d_ws, size_t ws_size,
                              hipStream_t stream) {
  const float* x    = (const float*)d_in[0];
  const float* w1r  = (const float*)d_in[1];
  const float* w1i  = (const float*)d_in[2];
  const float* w2r  = (const float*)d_in[3];
  const float* w2i  = (const float*)d_in[4];
  const float* bias = (const float*)d_in[5];
  float* y  = (float*)d_out;
  float* ws = (float*)d_ws;
  float* F   = ws + F_OFF;
  float* E   = ws + g_OFF;           // 32 KB
  float* E2c = ws + g_OFF + 8192;    // 64 KB
  float* T2f = ws + g_OFF + 24576;   // 32 KB

  hipLaunchKernelGGL(e_init_kernel, dim3(256), dim3(256), 0, stream, E);
  hipLaunchKernelGGL(fwd_kernel, dim3(Bb * CI), dim3(512), 0, stream, x, E, E2c, F);
  hipLaunchKernelGGL(bwd_kernel, dim3(Bb * CO * 2), dim3(512), 0, stream, F,
                     w1r, w1i, w2r, w2i, bias, T2f, y);
}